// Round 1
// baseline (410.076 us; speedup 1.0000x reference)
//
#include <hip/hip_runtime.h>
#include <hip/hip_bf16.h>
#include <math.h>

// Problem constants (match reference)
#define BB 512
#define SS 128
#define VV 1024
#define NROWS (BB * SS)   // 65536
#define PAD_IDX 0

// Workspace layout (bytes):
//   ce   : float[NROWS]  @ 0        (262144 B)
//   pred : int[NROWS]    @ 262144   (262144 B)
//   fac  : float[2]      @ 524288   (sum ce*w, sum w)
//   iac  : int[8]        @ 524352   (abslen, bi, tri, correct, total_chars, end_ok, len_eq, valid_tri)
#define OFF_CE    0
#define OFF_PRED  262144
#define OFF_FAC   524288
#define OFF_IAC   524352

// ---------------------------------------------------------------------------
// Kernel 0: zero the accumulators (ws is poisoned 0xAA before every launch)
__global__ void zero_acc(float* fac, int* iac) {
    int i = threadIdx.x;
    if (i < 2) fac[i] = 0.0f;
    if (i < 8) iac[i] = 0;
}

// ---------------------------------------------------------------------------
// Kernel 1: per-(b,s) row of V=1024 logits -> ce (smoothed, pad-masked), argmax
// One wave (64 lanes) per row; 4 waves per 256-thread block.
__global__ __launch_bounds__(256) void row_kernel(
    const float* __restrict__ logits, const int* __restrict__ tgt,
    float* __restrict__ ce, int* __restrict__ pred)
{
    const int wave = threadIdx.x >> 6;
    const int lane = threadIdx.x & 63;
    const int row  = blockIdx.x * 4 + wave;   // grid = NROWS/4
    const float* base = logits + (size_t)row * VV;

    // Load 16 floats/lane as 4x float4; element index = j*256 + lane*4 + k
    float4 v[4];
#pragma unroll
    for (int j = 0; j < 4; ++j)
        v[j] = reinterpret_cast<const float4*>(base)[j * 64 + lane];

    // ---- pass 1: max + argmax (first-occurrence tie-break, like jnp.argmax)
    float m = -INFINITY; int am = VV;
#pragma unroll
    for (int j = 0; j < 4; ++j) {
        const int idx0 = j * 256 + lane * 4;
        float xs[4] = {v[j].x, v[j].y, v[j].z, v[j].w};
#pragma unroll
        for (int k = 0; k < 4; ++k) {
            float x = xs[k]; int idx = idx0 + k;
            if (x > m || (x == m && idx < am)) { m = x; am = idx; }
        }
    }
#pragma unroll
    for (int off = 32; off > 0; off >>= 1) {
        float om = __shfl_xor(m, off, 64);
        int   oa = __shfl_xor(am, off, 64);
        if (om > m || (om == m && oa < am)) { m = om; am = oa; }
    }
    // all lanes now hold row max m and argmax am

    const int t = tgt[row];

    // ---- pass 2: sum exp(x-m), sum x, and gather x[target]
    float se = 0.0f, sx = 0.0f, xt = 0.0f;
#pragma unroll
    for (int j = 0; j < 4; ++j) {
        const int idx0 = j * 256 + lane * 4;
        float xs[4] = {v[j].x, v[j].y, v[j].z, v[j].w};
#pragma unroll
        for (int k = 0; k < 4; ++k) {
            float x = xs[k];
            se += __expf(x - m);
            sx += x;
            if (idx0 + k == t) xt = x;
        }
    }
#pragma unroll
    for (int off = 32; off > 0; off >>= 1) {
        se += __shfl_xor(se, off, 64);
        sx += __shfl_xor(sx, off, 64);
        xt += __shfl_xor(xt, off, 64);
    }

    if (lane == 0) {
        float lse    = m + __logf(se);
        float nll    = lse - xt;                       // -logp[target]
        float smooth = lse - sx * (1.0f / (float)VV);  // -mean(logp)
        float c = (t != PAD_IDX) ? (0.9f * nll + 0.1f * smooth) : 0.0f;
        ce[row]   = c;
        pred[row] = am;
    }
}

// ---------------------------------------------------------------------------
// Kernel 2: per-batch-row stats. One block (128 threads = 2 waves) per b.
__global__ __launch_bounds__(128) void batch_kernel(
    const int* __restrict__ tgt, const float* __restrict__ ce,
    const int* __restrict__ pred, float* __restrict__ fac, int* __restrict__ iac)
{
    const int b = blockIdx.x;
    const int s = threadIdx.x;
    const int wave = s >> 6, lane = s & 63;

    __shared__ int sh_t[SS], sh_p[SS];
    __shared__ int sL[2], sPL[2], sCor[2], sFront[2];
    __shared__ float sRW[2], sRCW[2];
    __shared__ int sRBi[2], sRTri[2];

    const int   t = tgt[b * SS + s];
    const int   p = pred[b * SS + s];
    const float c = ce[b * SS + s];
    sh_t[s] = t; sh_p[s] = p;

    unsigned long long bal;
    bal = __ballot(t != PAD_IDX);              if (!lane) sL[wave]     = __popcll(bal);
    bal = __ballot(p != PAD_IDX);              if (!lane) sPL[wave]    = __popcll(bal);
    bal = __ballot(p == t && t != PAD_IDX);    if (!lane) sCor[wave]   = __popcll(bal);
    bal = __ballot(t != PAD_IDX && s < SS-2);  if (!lane) sFront[wave] = __popcll(bal);
    __syncthreads();

    const int L    = sL[0] + sL[1];
    const int plen = sPL[0] + sPL[1];

    // position weights (pos == s)
    float Lf = fmaxf((float)L, 1.0f);
    float w  = (s < L) ? 1.0f + ((float)s / Lf) * 0.5f : 1.0f;
    if (s == L - 3 && L >= 3) w = 3.0f * 0.6f;
    if (s == L - 2 && L >= 2) w = 3.0f * 0.8f;
    if (s == L - 1 && L >= 1) w = 3.0f;
    float cw = c * w;

    // bigram / trigram (exact integer terms)
    int bi = 0, tri = 0;
    if (s < SS - 1) {
        int pe = (p == sh_p[s + 1]);
        int te = (t == sh_t[s + 1]);
        int sm = (p == t);
        bi = pe + te - 2 * (pe & te & sm);
        if (s < SS - 2) {
            int pe3 = pe & (sh_p[s + 1] == sh_p[s + 2]);
            int te3 = te & (sh_t[s + 1] == sh_t[s + 2]);
            tri = pe3 + te3 - 2 * (pe3 & te3 & sm);
        }
    }

    // block reduce w, cw, bi, tri
    float rw = w, rcw = cw; int rbi = bi, rtri = tri;
#pragma unroll
    for (int off = 32; off > 0; off >>= 1) {
        rw  += __shfl_xor(rw,  off, 64);
        rcw += __shfl_xor(rcw, off, 64);
        rbi += __shfl_xor(rbi, off, 64);
        rtri+= __shfl_xor(rtri,off, 64);
    }
    if (!lane) { sRW[wave] = rw; sRCW[wave] = rcw; sRBi[wave] = rbi; sRTri[wave] = rtri; }
    __syncthreads();

    if (s == 0) {
        float sumw  = sRW[0]  + sRW[1];
        float sumcw = sRCW[0] + sRCW[1];
        int bis  = sRBi[0]  + sRBi[1];
        int tris = sRTri[0] + sRTri[1];
        int cor  = sCor[0]  + sCor[1];
        int front= sFront[0]+ sFront[1];

        int end_idx = L - 1; if (end_idx < 0) end_idx = 0; if (end_idx > SS-1) end_idx = SS-1;
        int eok = (L > 0) && (sh_p[end_idx] == sh_t[end_idx]);

        atomicAdd(&fac[0], sumcw);
        atomicAdd(&fac[1], sumw);
        int d = plen - L; if (d < 0) d = -d;
        atomicAdd(&iac[0], d);
        atomicAdd(&iac[1], bis);
        atomicAdd(&iac[2], tris);
        atomicAdd(&iac[3], cor);
        atomicAdd(&iac[4], L);
        atomicAdd(&iac[5], eok ? 1 : 0);
        atomicAdd(&iac[6], (L == plen) ? 1 : 0);
        if (front > 0) atomicOr(&iac[7], 1);
    }
}

// ---------------------------------------------------------------------------
// Kernel 3: finalize the 4 scalars
__global__ void finalize(const float* __restrict__ fac, const int* __restrict__ iac,
                         float* __restrict__ out)
{
    if (threadIdx.x == 0 && blockIdx.x == 0) {
        float weighted = fac[0] / fac[1];
        float lp  = 0.1f * (float)iac[0] / (float)BB;
        float bi  = (float)iac[1] / ((float)BB * (float)(SS - 1) * (float)VV);
        float tri = (float)iac[2] / ((float)BB * (float)(SS - 2) * (float)VV);
        float cng = bi + (iac[7] ? tri : 0.0f);
        out[0] = weighted + lp + 0.2f * cng;                       // total_loss
        out[1] = iac[4] > 0 ? (float)iac[3] / (float)iac[4] : 0.0f; // char_acc
        out[2] = (float)iac[5] / (float)BB;                         // end_char_acc
        out[3] = (float)iac[6] / (float)BB;                         // length_acc
    }
}

// ---------------------------------------------------------------------------
extern "C" void kernel_launch(void* const* d_in, const int* in_sizes, int n_in,
                              void* d_out, int out_size, void* d_ws, size_t ws_size,
                              hipStream_t stream)
{
    const float* logits = (const float*)d_in[0];
    const int*   tgt    = (const int*)d_in[1];
    float* out = (float*)d_out;

    char* ws = (char*)d_ws;
    float* ce   = (float*)(ws + OFF_CE);
    int*   pred = (int*)  (ws + OFF_PRED);
    float* fac  = (float*)(ws + OFF_FAC);
    int*   iac  = (int*)  (ws + OFF_IAC);

    zero_acc<<<1, 64, 0, stream>>>(fac, iac);
    row_kernel<<<NROWS / 4, 256, 0, stream>>>(logits, tgt, ce, pred);
    batch_kernel<<<BB, SS, 0, stream>>>(tgt, ce, pred, fac, iac);
    finalize<<<1, 1, 0, stream>>>(fac, iac, out);
}